// Round 4
// baseline (833.404 us; speedup 1.0000x reference)
//
#include <hip/hip_runtime.h>

// Problem constants (match reference): B=4096 rows, C=32000 classes, fp32.
#define NUM_CLASSES 32000
#define C4 (NUM_CLASSES / 4)   // 8000 float4 per row
#define BLK 512                // 8 waves
#define PER_THREAD 16          // ceil(8000/512) = 16 (last iter partially masked)
#define ALPHA 0.95f

// Native clang vector type: __builtin_nontemporal_store requires this
// (HIP's float4 is a HIP_vector_type class and is rejected).
typedef float nfloat4 __attribute__((ext_vector_type(4)));

__global__ __launch_bounds__(BLK) void distill_kernel(
    const float* __restrict__ logits,
    const int* __restrict__ labels,
    float* __restrict__ out)
{
    const int row = blockIdx.x;
    const int tid = threadIdx.x;
    const float* __restrict__ rowp = logits + (size_t)row * NUM_CLASSES;
    float* __restrict__ outp = out + (size_t)row * NUM_CLASSES;
    const int label = labels[row];

    // ---- pass 1: load row into registers, accumulate partial sum ----
    float4 v[PER_THREAD];
    float lsum = 0.0f;
#pragma unroll
    for (int k = 0; k < PER_THREAD; ++k) {
        const int idx = k * BLK + tid;
        if (idx < C4) {
            v[k] = reinterpret_cast<const float4*>(rowp)[idx];
            lsum += (v[k].x + v[k].y) + (v[k].z + v[k].w);
        }
    }

    // ---- block reduction: wave shfl (64 lanes) then LDS across 8 waves ----
#pragma unroll
    for (int off = 32; off > 0; off >>= 1)
        lsum += __shfl_down(lsum, off);   // width defaults to warpSize=64

    __shared__ float wsum[BLK / 64];
    __shared__ float s_S;
    const int wave = tid >> 6;
    if ((tid & 63) == 0) wsum[wave] = lsum;
    __syncthreads();
    if (tid == 0) {
        float S = 0.0f;
#pragma unroll
        for (int w = 0; w < BLK / 64; ++w) S += wsum[w];
        s_S = S;
    }
    __syncthreads();

    const float S = s_S;
    const float t = rowp[label];               // uniform broadcast load (L2 hit)
    const float s = ALPHA / (1.0f + S - 2.0f * t);
    const float corr = 1.0f - s * S;           // out[label] = s*t + corr

    // ---- pass 2: scale from registers, fix label element, write ----
#pragma unroll
    for (int k = 0; k < PER_THREAD; ++k) {
        const int idx = k * BLK + tid;
        if (idx < C4) {
            const int j = idx << 2;           // global column of component .x
            nfloat4 o;
            o.x = s * v[k].x + ((j + 0) == label ? corr : 0.0f);
            o.y = s * v[k].y + ((j + 1) == label ? corr : 0.0f);
            o.z = s * v[k].z + ((j + 2) == label ? corr : 0.0f);
            o.w = s * v[k].w + ((j + 3) == label ? corr : 0.0f);
            // Output is streamed and never re-read: nontemporal store keeps
            // it from evicting useful L2/L3 lines.
            __builtin_nontemporal_store(o, reinterpret_cast<nfloat4*>(outp) + idx);
        }
    }
}

extern "C" void kernel_launch(void* const* d_in, const int* in_sizes, int n_in,
                              void* d_out, int out_size, void* d_ws, size_t ws_size,
                              hipStream_t stream) {
    const float* logits = (const float*)d_in[0];
    const int* labels   = (const int*)d_in[1];
    float* out          = (float*)d_out;

    const int rows = in_sizes[1];              // 4096
    // NUM_CLASSES hardcoded (in_sizes[0]/rows == 32000 per reference).

    distill_kernel<<<rows, BLK, 0, stream>>>(logits, labels, out);
}